// Round 6
// baseline (322.256 us; speedup 1.0000x reference)
//
#include <hip/hip_runtime.h>
#include <hip/hip_bf16.h>
#include <stdint.h>

typedef float f32x4_t __attribute__((ext_vector_type(4)));
typedef short bf16x8_t __attribute__((ext_vector_type(8)));

#define MFMA16(a, b, c) __builtin_amdgcn_mfma_f32_16x16x32_bf16((a), (b), (c), 0, 0, 0)

static __device__ __forceinline__ unsigned short f2bf(float f) {
  union { float f; unsigned int u; } v;
  v.f = f;
  unsigned int u = v.u;
  unsigned int r = (u + 0x7fffu + ((u >> 16) & 1u)) >> 16;  // RNE
  return (unsigned short)r;
}

static __device__ __forceinline__ void gll16(const unsigned short* g, unsigned short* l) {
  __builtin_amdgcn_global_load_lds(
      (const __attribute__((address_space(1))) unsigned int*)g,
      (__attribute__((address_space(3))) unsigned int*)l, 16, 0, 0);
}

// ---------------- weights f32 -> bf16 (4 weights in one launch) ----------------
__global__ __launch_bounds__(256) void cvt4_kernel(const float* __restrict__ s0,
                                                   const float* __restrict__ s1,
                                                   const float* __restrict__ s2,
                                                   const float* __restrict__ s3,
                                                   unsigned short* __restrict__ dst) {
  const int i = blockIdx.x * 256 + threadIdx.x;  // < 262144
  const float* src = (blockIdx.y == 0) ? s0 : (blockIdx.y == 1) ? s1 : (blockIdx.y == 2) ? s2 : s3;
  float4 v = ((const float4*)src)[i];
  ushort4 o;
  o.x = f2bf(v.x); o.y = f2bf(v.y); o.z = f2bf(v.z); o.w = f2bf(v.w);
  ((ushort4*)(dst + (size_t)blockIdx.y * 1048576))[i] = o;
}

// ---------------- LayerNorm: x[row][1024] f32 -> xn bf16 ----------------
__global__ __launch_bounds__(256) void ln_kernel(const float* __restrict__ x,
                                                 unsigned short* __restrict__ xn) {
  const int row = blockIdx.x;
  const int tid = threadIdx.x, w = tid >> 6, lane = tid & 63;
  const float4 v = ((const float4*)(x + (size_t)row * 1024))[tid];
  float s = v.x + v.y + v.z + v.w;
  float s2 = v.x * v.x + v.y * v.y + v.z * v.z + v.w * v.w;
#pragma unroll
  for (int m = 32; m; m >>= 1) {
    s += __shfl_xor(s, m, 64);
    s2 += __shfl_xor(s2, m, 64);
  }
  __shared__ float red[2][4];
  if (lane == 0) { red[0][w] = s; red[1][w] = s2; }
  __syncthreads();
  const float S = red[0][0] + red[0][1] + red[0][2] + red[0][3];
  const float S2 = red[1][0] + red[1][1] + red[1][2] + red[1][3];
  const float mu = S * (1.0f / 1024.0f);
  const float var = S2 * (1.0f / 1024.0f) - mu * mu;
  const float rstd = rsqrtf(var + 1e-5f);
  ushort4 o;
  o.x = f2bf((v.x - mu) * rstd);
  o.y = f2bf((v.y - mu) * rstd);
  o.z = f2bf((v.z - mu) * rstd);
  o.w = f2bf((v.w - mu) * rstd);
  ((ushort4*)(xn + (size_t)row * 1024))[tid] = o;
}

// ---------------- pipelined GEMM: C[M][N] = A[M][K] * B[N][K]^T ----------------
// Tile 256(M) x 128(N) x BK=64. 512 thr = 8 waves (4M x 2N), wave owns 64x64.
// Ring of 3 LDS K-tile buffers; per iter: issue stage(t+2); consume(t);
// s_waitcnt vmcnt(6); s_barrier. Never vmcnt(0) in main loop (T3+T4).
// Read-side chunk-XOR paired with pre-swizzled global staging source (T2/m173).
// MODE 3: fused QKV epilogue (N=3072): bn<8 -> Qb; bn<16 -> Kb; else Vt plain
//         transposed per-(b,h) tile [64][256] (V consumed from global now).
// MODE 2: f32 d_out = acc + bias[col] + resid
template <int MODE>
__global__ __launch_bounds__(512, 1) void gemm_pipe(
    const unsigned short* __restrict__ A, const unsigned short* __restrict__ B,
    unsigned short* __restrict__ Qo, unsigned short* __restrict__ Ko,
    unsigned short* __restrict__ Vo, float* __restrict__ Cf,
    const float* __restrict__ bias, const float* __restrict__ resid, int GX) {
  constexpr int K = 1024;
  constexpr int NT = 16;  // K / 64
  __shared__ __align__(16) unsigned short lds[73728];  // A: 3*16384, B base 49152: 3*8192
  const int tid = threadIdx.x;
  const int wv = tid >> 6, lane = tid & 63;
  const int l15 = lane & 15, l4 = lane >> 4;
  const int wr = wv >> 1, wc = wv & 1;
  // bijective XCD swizzle (nwg % 8 == 0 for both grids)
  const int fid = blockIdx.y * GX + blockIdx.x;
  const int cpx = (GX * gridDim.y) >> 3;
  const int swz = (fid & 7) * cpx + (fid >> 3);
  const int bm = swz / GX, bn = swz % GX;

  // staging source: 8-lane groups cover one row's 8 chunks, chunk pre-XOR'd by row&7
  const int srow = wv * 8 + (lane >> 3);
  const int schunk = ((lane & 7) ^ (lane >> 3)) * 8;
  const unsigned short* Ag = A + (size_t)(bm * 256 + srow) * K + schunk;
  const unsigned short* Bg = B + (size_t)(bn * 128 + srow) * K + schunk;

  f32x4_t acc[4][4];
#pragma unroll
  for (int i = 0; i < 4; ++i)
#pragma unroll
    for (int j = 0; j < 4; ++j) acc[i][j] = (f32x4_t){0.f, 0.f, 0.f, 0.f};

#define STAGE(tt, slot)                                                          \
  {                                                                              \
    const unsigned short* As_ = Ag + (tt)*64;                                    \
    const unsigned short* Bs_ = Bg + (tt)*64;                                    \
    _Pragma("unroll") for (int r = 0; r < 4; ++r)                                \
        gll16(As_ + (size_t)(r * 64) * K, &lds[(slot)*16384 + r * 4096 + wv * 512]); \
    _Pragma("unroll") for (int r = 0; r < 2; ++r)                                \
        gll16(Bs_ + (size_t)(r * 64) * K,                                        \
              &lds[49152 + (slot)*8192 + r * 4096 + wv * 512]);                  \
  }

#define CONSUME(slot)                                                            \
  {                                                                              \
    const unsigned short* As_ = &lds[(slot)*16384];                              \
    const unsigned short* Bs_ = &lds[49152 + (slot)*8192];                       \
    _Pragma("unroll") for (int kk = 0; kk < 2; ++kk) {                           \
      const int cx = 8 * (((kk * 4 + l4) ^ (l15 & 7)));                          \
      bf16x8_t af[4], bf[4];                                                     \
      _Pragma("unroll") for (int m = 0; m < 4; ++m)                              \
          af[m] = *(const bf16x8_t*)&As_[(wr * 64 + m * 16 + l15) * 64 + cx];    \
      _Pragma("unroll") for (int n = 0; n < 4; ++n)                              \
          bf[n] = *(const bf16x8_t*)&Bs_[(wc * 64 + n * 16 + l15) * 64 + cx];    \
      __builtin_amdgcn_s_setprio(1);                                             \
      _Pragma("unroll") for (int m = 0; m < 4; ++m)                              \
          _Pragma("unroll") for (int n = 0; n < 4; ++n)                          \
              acc[m][n] = MFMA16(af[m], bf[n], acc[m][n]);                       \
      __builtin_amdgcn_s_setprio(0);                                             \
    }                                                                            \
  }

  STAGE(0, 0);
  STAGE(1, 1);
  asm volatile("s_waitcnt vmcnt(6)" ::: "memory");
  __builtin_amdgcn_s_barrier();
  asm volatile("" ::: "memory");

#pragma unroll 1
  for (int t = 0; t < NT - 2; ++t) {
    const int s = t % 3;
    const int sp = (t + 2) % 3;
    STAGE(t + 2, sp);
    CONSUME(s);
    asm volatile("s_waitcnt vmcnt(6)" ::: "memory");
    __builtin_amdgcn_s_barrier();
    asm volatile("" ::: "memory");
  }
  CONSUME((NT - 2) % 3);
  asm volatile("s_waitcnt vmcnt(0)" ::: "memory");
  __builtin_amdgcn_s_barrier();
  asm volatile("" ::: "memory");
  CONSUME((NT - 1) % 3);

#undef STAGE
#undef CONSUME

  const int rbase = bm * 256 + wr * 64;
  const int cbase = bn * 128 + wc * 64;
  if constexpr (MODE == 3) {
    if (bn < 16) {  // Q or K: plain bf16 rows
      unsigned short* Out = (bn < 8) ? Qo : Ko;
      const int coff = (bn < 8) ? 0 : 1024;
#pragma unroll
      for (int i = 0; i < 4; ++i) {
        const int row0 = rbase + i * 16 + l4 * 4;
#pragma unroll
        for (int j = 0; j < 4; ++j) {
          const int col = cbase + j * 16 + l15 - coff;
#pragma unroll
          for (int r = 0; r < 4; ++r) Out[(size_t)(row0 + r) * 1024 + col] = f2bf(acc[i][j][r]);
        }
      }
    } else {  // V: plain transposed per-(b,h) tile [64][256]
#pragma unroll
      for (int i = 0; i < 4; ++i) {
        const int row0 = rbase + i * 16 + l4 * 4;
        const int bb = row0 >> 8, s0 = row0 & 255;
#pragma unroll
        for (int j = 0; j < 4; ++j) {
          const int e = cbase + j * 16 + l15 - 2048;  // 0..1023 (h*64 + d)
          ushort4 pk;
          pk.x = f2bf(acc[i][j][0]); pk.y = f2bf(acc[i][j][1]);
          pk.z = f2bf(acc[i][j][2]); pk.w = f2bf(acc[i][j][3]);
          *(ushort4*)&Vo[((size_t)bb * 1024 + e) * 256 + s0] = pk;
        }
      }
    }
  } else {  // MODE 2
#pragma unroll
    for (int i = 0; i < 4; ++i) {
      const int row0 = rbase + i * 16 + l4 * 4;
#pragma unroll
      for (int j = 0; j < 4; ++j) {
        const int col = cbase + j * 16 + l15;
        const float bo = bias[col];
#pragma unroll
        for (int r = 0; r < 4; ++r) {
          const size_t idx = (size_t)(row0 + r) * 1024 + col;
          Cf[idx] = acc[i][j][r] + bo + resid[idx];
        }
      }
    }
  }
}

// ---------------- fused attention: barrier-free wave tasks ----------------
// grid (64 taskgroups, 64 b) x 256 thr. Wave task id = blockIdx.x*4 + w:
// h = id & 15, q-chunk = id >> 4 (16 rows). K and V read directly from global
// (L2/L3-hot fragment loads, 64B granule per l4-group). LDS only for P
// round-trip (wave-local) + state. No main-loop barriers; 16 waves/CU via
// __launch_bounds__(256,4). exp via exp2 with log2e-prescaled biases.
__global__ __launch_bounds__(256, 4) void attn_kernel(
    const unsigned short* __restrict__ Q, const unsigned short* __restrict__ K,
    const unsigned short* __restrict__ Vt, unsigned short* __restrict__ O,
    const int* __restrict__ state, const float* __restrict__ etb,
    const float* __restrict__ srb, const float* __restrict__ rsb) {
  const int b = blockIdx.y;
  const int tid = threadIdx.x, w = tid >> 6, lane = tid & 63;
  const int l15 = lane & 15, l4 = lane >> 4;
  const int id = blockIdx.x * 4 + w;  // 0..255
  const int h = id & 15;
  const int qrow0 = (id >> 4) * 16;

  __shared__ __align__(16) unsigned short Ps[4][16 * 136];  // 17 KB, stride-136 skew
  __shared__ int state_s[256];                              // 1 KB

  state_s[tid] = (tid >= 3) ? state[b * 253 + tid - 3] : 0x7fffffff;
  constexpr float L2E = 1.4426950408889634f;
  const float e0 = etb[0] * L2E, e1 = etb[1] * L2E, e2 = etb[2] * L2E, e3 = etb[3] * L2E;
  const float sr0 = srb[0] * L2E, sr1 = srb[1] * L2E;
  const float rs0 = rsb[0] * L2E, rs2 = rsb[2] * L2E;
  __syncthreads();

  const size_t qoff = (size_t)(b * 256 + qrow0 + l15) * 1024 + h * 64 + l4 * 8;
  const bf16x8_t qf0 = *(const bf16x8_t*)(Q + qoff);
  const bf16x8_t qf1 = *(const bf16x8_t*)(Q + qoff + 32);

  const int qr0 = qrow0 + l4 * 4;
  int sq[4];
#pragma unroll
  for (int r = 0; r < 4; ++r) sq[r] = state_s[qr0 + r];

  f32x4_t oacc[4];
#pragma unroll
  for (int n = 0; n < 4; ++n) oacc[n] = (f32x4_t){0.f, 0.f, 0.f, 0.f};
  float rsum[4] = {0.f, 0.f, 0.f, 0.f};
  const unsigned short* Vb = Vt + ((size_t)b * 1024 + h * 64) * 256;

#pragma unroll
  for (int half = 0; half < 2; ++half) {
    // ---- QK^T for 128 k-columns (K direct from global) ----
    f32x4_t sc[8];
#pragma unroll
    for (int f = 0; f < 8; ++f) sc[f] = (f32x4_t){0.f, 0.f, 0.f, 0.f};
    const unsigned short* Kb2 =
        K + (size_t)(b * 256 + half * 128) * 1024 + h * 64 + l4 * 8;
#pragma unroll
    for (int f = 0; f < 8; ++f) {
      const unsigned short* kp = Kb2 + (size_t)(f * 16 + l15) * 1024;
      sc[f] = MFMA16(qf0, *(const bf16x8_t*)kp, sc[f]);
      sc[f] = MFMA16(qf1, *(const bf16x8_t*)(kp + 32), sc[f]);
    }

    // ---- bias + exp2 + unnormalized P write + partial row-sum ----
#pragma unroll
    for (int f = 0; f < 8; ++f) {
      const int kcol = half * 128 + f * 16 + l15;
      const bool kd = kcol >= 3;
      const int skc = state_s[kcol];
#pragma unroll
      for (int r = 0; r < 4; ++r) {
        const int qrow = qr0 + r;
        float bd = e0 + ((skc == sq[r]) ? sr0 : sr1) + ((qrow < kcol) ? rs0 : rs2);
        float bv = (qrow >= 3) ? (kd ? bd : e1) : (kd ? e2 : e3);
        bv = (qrow == kcol) ? 0.f : bv;
        const float p = exp2f(fmaf(sc[f][r], 0.18033688011112042f, bv));
        rsum[r] += p;
        Ps[w][(l4 * 4 + r) * 136 + f * 16 + l15] = f2bf(p);
      }
    }

    // ---- PV for this half (P wave-local LDS; V direct from global) ----
#pragma unroll
    for (int kbl = 0; kbl < 4; ++kbl) {
      const bf16x8_t pf = *(const bf16x8_t*)&Ps[w][l15 * 136 + kbl * 32 + l4 * 8];
      const int kb = half * 4 + kbl;
#pragma unroll
      for (int n = 0; n < 4; ++n) {
        const int d = n * 16 + l15;
        const bf16x8_t vf = *(const bf16x8_t*)(Vb + (size_t)d * 256 + kb * 32 + l4 * 8);
        oacc[n] = MFMA16(pf, vf, oacc[n]);
      }
    }
  }

  // ---- row-sum reduce over l15 group, scale, store ----
#pragma unroll
  for (int m = 1; m < 16; m <<= 1)
#pragma unroll
    for (int r = 0; r < 4; ++r) rsum[r] += __shfl_xor(rsum[r], m, 64);
  float rinv[4];
#pragma unroll
  for (int r = 0; r < 4; ++r) rinv[r] = 1.0f / rsum[r];
  unsigned short* Op = O + (size_t)(b * 256 + qr0) * 1024 + h * 64;
#pragma unroll
  for (int n = 0; n < 4; ++n)
#pragma unroll
    for (int r = 0; r < 4; ++r)
      Op[(size_t)r * 1024 + n * 16 + l15] = f2bf(oacc[n][r] * rinv[r]);
}

extern "C" void kernel_launch(void* const* d_in, const int* in_sizes, int n_in,
                              void* d_out, int out_size, void* d_ws, size_t ws_size,
                              hipStream_t stream) {
  const float* x = (const float*)d_in[0];
  const int* state = (const int*)d_in[1];
  const float* WQ = (const float*)d_in[3];
  const float* WK = (const float*)d_in[4];
  const float* WV = (const float*)d_in[5];
  const float* WO = (const float*)d_in[6];
  const float* bO = (const float*)d_in[7];
  const float* etb = (const float*)d_in[8];
  const float* srb = (const float*)d_in[9];
  const float* rsb = (const float*)d_in[10];

  char* ws = (char*)d_ws;
  unsigned short* xn = (unsigned short*)(ws);                        // 32 MiB (reused as attn_out)
  unsigned short* Vt = (unsigned short*)(ws + (size_t)(32 << 20));   // 32 MiB
  unsigned short* WQKVb = (unsigned short*)(ws + (size_t)(64 << 20));// 6 MiB (WQ|WK|WV)
  unsigned short* WOb = WQKVb + (3 << 20);                           // 2 MiB
  unsigned short* Qb = (unsigned short*)d_out;  // scratch in d_out: 32 MiB
  unsigned short* Kb = Qb + (16 << 20);         // + 32 MiB

  cvt4_kernel<<<dim3(1024, 4), 256, 0, stream>>>(WQ, WK, WV, WO, WQKVb);
  ln_kernel<<<16384, 256, 0, stream>>>(x, xn);

  gemm_pipe<3><<<dim3(24, 64), 512, 0, stream>>>(xn, WQKVb, Qb, Kb, Vt, nullptr,
                                                 nullptr, nullptr, 24);

  attn_kernel<<<dim3(64, 64), 256, 0, stream>>>(Qb, Kb, Vt, xn, state, etb, srb, rsb);

  gemm_pipe<2><<<dim3(8, 64), 512, 0, stream>>>(xn, WOb, nullptr, nullptr, nullptr,
                                                (float*)d_out, bO, x, 8);
}

// Round 8
// 270.625 us; speedup vs baseline: 1.1908x; 1.1908x over previous
//
#include <hip/hip_runtime.h>
#include <hip/hip_bf16.h>
#include <stdint.h>

typedef float f32x4_t __attribute__((ext_vector_type(4)));
typedef short bf16x8_t __attribute__((ext_vector_type(8)));

#define MFMA16(a, b, c) __builtin_amdgcn_mfma_f32_16x16x32_bf16((a), (b), (c), 0, 0, 0)

static __device__ __forceinline__ unsigned short f2bf(float f) {
  union { float f; unsigned int u; } v;
  v.f = f;
  unsigned int u = v.u;
  unsigned int r = (u + 0x7fffu + ((u >> 16) & 1u)) >> 16;  // RNE
  return (unsigned short)r;
}

static __device__ __forceinline__ void gll16(const unsigned short* g, unsigned short* l) {
  __builtin_amdgcn_global_load_lds(
      (const __attribute__((address_space(1))) unsigned int*)g,
      (__attribute__((address_space(3))) unsigned int*)l, 16, 0, 0);
}

// ---------------- weights f32 -> bf16 (4 weights in one launch) ----------------
__global__ __launch_bounds__(256) void cvt4_kernel(const float* __restrict__ s0,
                                                   const float* __restrict__ s1,
                                                   const float* __restrict__ s2,
                                                   const float* __restrict__ s3,
                                                   unsigned short* __restrict__ dst) {
  const int i = blockIdx.x * 256 + threadIdx.x;  // < 262144
  const float* src = (blockIdx.y == 0) ? s0 : (blockIdx.y == 1) ? s1 : (blockIdx.y == 2) ? s2 : s3;
  float4 v = ((const float4*)src)[i];
  ushort4 o;
  o.x = f2bf(v.x); o.y = f2bf(v.y); o.z = f2bf(v.z); o.w = f2bf(v.w);
  ((ushort4*)(dst + (size_t)blockIdx.y * 1048576))[i] = o;
}

// ---------------- LayerNorm: x[row][1024] f32 -> xn bf16 ----------------
__global__ __launch_bounds__(256) void ln_kernel(const float* __restrict__ x,
                                                 unsigned short* __restrict__ xn) {
  const int row = blockIdx.x;
  const int tid = threadIdx.x, w = tid >> 6, lane = tid & 63;
  const float4 v = ((const float4*)(x + (size_t)row * 1024))[tid];
  float s = v.x + v.y + v.z + v.w;
  float s2 = v.x * v.x + v.y * v.y + v.z * v.z + v.w * v.w;
#pragma unroll
  for (int m = 32; m; m >>= 1) {
    s += __shfl_xor(s, m, 64);
    s2 += __shfl_xor(s2, m, 64);
  }
  __shared__ float red[2][4];
  if (lane == 0) { red[0][w] = s; red[1][w] = s2; }
  __syncthreads();
  const float S = red[0][0] + red[0][1] + red[0][2] + red[0][3];
  const float S2 = red[1][0] + red[1][1] + red[1][2] + red[1][3];
  const float mu = S * (1.0f / 1024.0f);
  const float var = S2 * (1.0f / 1024.0f) - mu * mu;
  const float rstd = rsqrtf(var + 1e-5f);
  ushort4 o;
  o.x = f2bf((v.x - mu) * rstd);
  o.y = f2bf((v.y - mu) * rstd);
  o.z = f2bf((v.z - mu) * rstd);
  o.w = f2bf((v.w - mu) * rstd);
  ((ushort4*)(xn + (size_t)row * 1024))[tid] = o;
}

// ---------------- pipelined GEMM: C[M][N] = A[M][K] * B[N][K]^T ----------------
// Tile 256(M) x 128(N) x BK=64. 512 thr = 8 waves (4M x 2N), wave owns 64x64.
// Ring of 3 LDS K-tile buffers; per iter: issue stage(t+2); consume(t);
// s_waitcnt vmcnt(6); sched_barrier(0); s_barrier; sched_barrier(0).
// Never vmcnt(0) in main loop (T3+T4). Read-side chunk-XOR paired with
// pre-swizzled global staging source (T2/m173).
// MODE 3: fused QKV epilogue (N=3072): bn<8 -> Qb plain rows; bn<16 -> Kf in
//   MFMA-FRAGMENT order (attn QK B-frag = 1KB coalesced wave load);
//   else -> Vf fragment order.
// MODE 2: f32 d_out = acc + bias[col] + resid
template <int MODE>
__global__ __launch_bounds__(512, 1) void gemm_pipe(
    const unsigned short* __restrict__ A, const unsigned short* __restrict__ B,
    unsigned short* __restrict__ Qo, unsigned short* __restrict__ Ko,
    unsigned short* __restrict__ Vo, float* __restrict__ Cf,
    const float* __restrict__ bias, const float* __restrict__ resid, int GX) {
  constexpr int K = 1024;
  constexpr int NT = 16;  // K / 64
  __shared__ __align__(16) unsigned short lds[73728];  // A: 3*16384, B base 49152: 3*8192
  const int tid = threadIdx.x;
  const int wv = tid >> 6, lane = tid & 63;
  const int l15 = lane & 15, l4 = lane >> 4;
  const int wr = wv >> 1, wc = wv & 1;
  // bijective XCD swizzle (nwg % 8 == 0 for both grids)
  const int fid = blockIdx.y * GX + blockIdx.x;
  const int cpx = (GX * gridDim.y) >> 3;
  const int swz = (fid & 7) * cpx + (fid >> 3);
  const int bm = swz / GX, bn = swz % GX;

  // staging source: 8-lane groups cover one row's 8 chunks, chunk pre-XOR'd by row&7
  const int srow = wv * 8 + (lane >> 3);
  const int schunk = ((lane & 7) ^ (lane >> 3)) * 8;
  const unsigned short* Ag = A + (size_t)(bm * 256 + srow) * K + schunk;
  const unsigned short* Bg = B + (size_t)(bn * 128 + srow) * K + schunk;

  f32x4_t acc[4][4];
#pragma unroll
  for (int i = 0; i < 4; ++i)
#pragma unroll
    for (int j = 0; j < 4; ++j) acc[i][j] = (f32x4_t){0.f, 0.f, 0.f, 0.f};

#define STAGE(tt, slot)                                                          \
  {                                                                              \
    const unsigned short* As_ = Ag + (tt)*64;                                    \
    const unsigned short* Bs_ = Bg + (tt)*64;                                    \
    _Pragma("unroll") for (int r = 0; r < 4; ++r)                                \
        gll16(As_ + (size_t)(r * 64) * K, &lds[(slot)*16384 + r * 4096 + wv * 512]); \
    _Pragma("unroll") for (int r = 0; r < 2; ++r)                                \
        gll16(Bs_ + (size_t)(r * 64) * K,                                        \
              &lds[49152 + (slot)*8192 + r * 4096 + wv * 512]);                  \
  }

#define CONSUME(slot)                                                            \
  {                                                                              \
    const unsigned short* As_ = &lds[(slot)*16384];                              \
    const unsigned short* Bs_ = &lds[49152 + (slot)*8192];                       \
    _Pragma("unroll") for (int kk = 0; kk < 2; ++kk) {                           \
      const int cx = 8 * (((kk * 4 + l4) ^ (l15 & 7)));                          \
      bf16x8_t af[4], bf[4];                                                     \
      _Pragma("unroll") for (int m = 0; m < 4; ++m)                              \
          af[m] = *(const bf16x8_t*)&As_[(wr * 64 + m * 16 + l15) * 64 + cx];    \
      _Pragma("unroll") for (int n = 0; n < 4; ++n)                              \
          bf[n] = *(const bf16x8_t*)&Bs_[(wc * 64 + n * 16 + l15) * 64 + cx];    \
      __builtin_amdgcn_s_setprio(1);                                             \
      _Pragma("unroll") for (int m = 0; m < 4; ++m)                              \
          _Pragma("unroll") for (int n = 0; n < 4; ++n)                          \
              acc[m][n] = MFMA16(af[m], bf[n], acc[m][n]);                       \
      __builtin_amdgcn_s_setprio(0);                                             \
    }                                                                            \
  }

#define RING_SYNC(N)                                            \
  asm volatile("s_waitcnt vmcnt(" #N ")" ::: "memory");         \
  __builtin_amdgcn_sched_barrier(0);                            \
  __builtin_amdgcn_s_barrier();                                 \
  __builtin_amdgcn_sched_barrier(0);                            \
  asm volatile("" ::: "memory");

  STAGE(0, 0);
  STAGE(1, 1);
  RING_SYNC(6);

#pragma unroll 1
  for (int t = 0; t < NT - 2; ++t) {
    const int s = t % 3;
    const int sp = (t + 2) % 3;
    STAGE(t + 2, sp);
    CONSUME(s);
    RING_SYNC(6);
  }
  CONSUME((NT - 2) % 3);
  RING_SYNC(0);
  CONSUME((NT - 1) % 3);

#undef STAGE
#undef CONSUME
#undef RING_SYNC

  const int rbase = bm * 256 + wr * 64;
  const int cbase = bn * 128 + wc * 64;
  if constexpr (MODE == 3) {
    if (bn < 8) {  // Q: plain bf16 rows
#pragma unroll
      for (int i = 0; i < 4; ++i) {
        const int row0 = rbase + i * 16 + l4 * 4;
#pragma unroll
        for (int j = 0; j < 4; ++j) {
          const int col = cbase + j * 16 + l15;
#pragma unroll
          for (int r = 0; r < 4; ++r) Qo[(size_t)(row0 + r) * 1024 + col] = f2bf(acc[i][j][r]);
        }
      }
    } else if (bn < 16) {  // K fragment layout: [(b*16+h)*16384 + (((fg*2+hd)*4+dc)*16+sl)*8+de]
      const int h = (bn - 8) * 2 + wc;
      unsigned short* Kfb = Ko + ((size_t)(bm * 16 + h)) * 16384;
#pragma unroll
      for (int i = 0; i < 4; ++i) {
        const int fg = wr * 4 + i;   // token group (s&255)>>4
        const int sl0 = l4 * 4;      // s&15 base (+r)
#pragma unroll
        for (int j = 0; j < 4; ++j) {
          const int d = j * 16 + l15;                     // 0..63
          const int hd = d >> 5, dc = (d >> 3) & 3, de = d & 7;
          unsigned short* p = Kfb + ((((fg * 2 + hd) * 4 + dc) * 16 + sl0) * 8 + de);
#pragma unroll
          for (int r = 0; r < 4; ++r) p[r * 8] = f2bf(acc[i][j][r]);
        }
      }
    } else {  // V fragment layout: [(b*16+h)*16384 + (((kb*4+n)*4+l4p)*16+l15)*8+de0..3]
      const int h = (bn - 16) * 2 + wc;
      unsigned short* Vfb = Vo + ((size_t)(bm * 16 + h)) * 16384;
#pragma unroll
      for (int i = 0; i < 4; ++i) {
        const int sb = wr * 64 + i * 16;                  // s_local base
        const int kb = sb >> 5;
        const int l4p = ((sb >> 3) & 3) | (l4 >> 1);
        const int de0 = (l4 & 1) * 4;
#pragma unroll
        for (int j = 0; j < 4; ++j) {  // n = j, l15' = l15
          ushort4 pk;
          pk.x = f2bf(acc[i][j][0]); pk.y = f2bf(acc[i][j][1]);
          pk.z = f2bf(acc[i][j][2]); pk.w = f2bf(acc[i][j][3]);
          *(ushort4*)&Vfb[(((kb * 4 + j) * 4 + l4p) * 16 + l15) * 8 + de0] = pk;
        }
      }
    }
  } else {  // MODE 2
#pragma unroll
    for (int i = 0; i < 4; ++i) {
      const int row0 = rbase + i * 16 + l4 * 4;
#pragma unroll
      for (int j = 0; j < 4; ++j) {
        const int col = cbase + j * 16 + l15;
        const float bo = bias[col];
#pragma unroll
        for (int r = 0; r < 4; ++r) {
          const size_t idx = (size_t)(row0 + r) * 1024 + col;
          Cf[idx] = acc[i][j][r] + bo + resid[idx];
        }
      }
    }
  }
}

// ---------------- fused attention: barrier-free wave tasks, coalesced frags ----
// grid (64, 64 b) x 256 thr. Wave task id = blockIdx.x*4 + w: h = id & 15,
// q-chunk = id >> 4 (16 rows). K/V in fragment order -> every load is
// base + lane*16B (1KB coalesced per instruction), batched 8 at a time.
// Ps double-buffered per half (no WAR reuse). No main-loop barriers.
__global__ __launch_bounds__(256, 4) void attn_kernel(
    const unsigned short* __restrict__ Q, const unsigned short* __restrict__ Kf,
    const unsigned short* __restrict__ Vf, unsigned short* __restrict__ O,
    const int* __restrict__ state, const float* __restrict__ etb,
    const float* __restrict__ srb, const float* __restrict__ rsb) {
  const int b = blockIdx.y;
  const int tid = threadIdx.x, w = tid >> 6, lane = tid & 63;
  const int l15 = lane & 15, l4 = lane >> 4;
  const int id = blockIdx.x * 4 + w;  // 0..255
  const int h = id & 15;
  const int qrow0 = (id >> 4) * 16;

  __shared__ __align__(16) unsigned short Ps[4][2][16 * 136];  // 34.8 KB, dbuf per half
  __shared__ int state_s[256];                                 // 1 KB

  state_s[tid] = (tid >= 3) ? state[b * 253 + tid - 3] : 0x7fffffff;
  constexpr float L2E = 1.4426950408889634f;
  const float e0 = etb[0] * L2E, e1 = etb[1] * L2E, e2 = etb[2] * L2E, e3 = etb[3] * L2E;
  const float sr0 = srb[0] * L2E, sr1 = srb[1] * L2E;
  const float rs0 = rsb[0] * L2E, rs2 = rsb[2] * L2E;
  __syncthreads();

  const size_t qoff = (size_t)(b * 256 + qrow0 + l15) * 1024 + h * 64 + l4 * 8;
  const bf16x8_t qf0 = *(const bf16x8_t*)(Q + qoff);
  const bf16x8_t qf1 = *(const bf16x8_t*)(Q + qoff + 32);

  const unsigned short* Kb_ = Kf + ((size_t)(b * 16 + h)) * 16384 + lane * 8;
  const unsigned short* Vb_ = Vf + ((size_t)(b * 16 + h)) * 16384 + lane * 8;

  const int qr0 = qrow0 + l4 * 4;
  int sq[4];
#pragma unroll
  for (int r = 0; r < 4; ++r) sq[r] = state_s[qr0 + r];

  f32x4_t oacc[4];
#pragma unroll
  for (int n = 0; n < 4; ++n) oacc[n] = (f32x4_t){0.f, 0.f, 0.f, 0.f};
  float rsum[4] = {0.f, 0.f, 0.f, 0.f};

#pragma unroll
  for (int half = 0; half < 2; ++half) {
    // ---- QK^T for 128 k-cols: K frag loads in 2 batches of 8 (8KB seq each) ----
    f32x4_t sc[8];
#pragma unroll
    for (int f = 0; f < 8; ++f) sc[f] = (f32x4_t){0.f, 0.f, 0.f, 0.f};
#pragma unroll
    for (int qtr = 0; qtr < 2; ++qtr) {
      bf16x8_t kr[8];
#pragma unroll
      for (int i = 0; i < 8; ++i)
        kr[i] = *(const bf16x8_t*)(Kb_ + (size_t)(half * 16 + qtr * 8 + i) * 512);
#pragma unroll
      for (int f = 0; f < 4; ++f) {
        sc[qtr * 4 + f] = MFMA16(qf0, kr[2 * f], sc[qtr * 4 + f]);
        sc[qtr * 4 + f] = MFMA16(qf1, kr[2 * f + 1], sc[qtr * 4 + f]);
      }
    }

    // ---- bias + exp2 + unnormalized P write + partial row-sum ----
#pragma unroll
    for (int f = 0; f < 8; ++f) {
      const int kcol = half * 128 + f * 16 + l15;
      const bool kd = kcol >= 3;
      const int skc = state_s[kcol];
#pragma unroll
      for (int r = 0; r < 4; ++r) {
        const int qrow = qr0 + r;
        float bd = e0 + ((skc == sq[r]) ? sr0 : sr1) + ((qrow < kcol) ? rs0 : rs2);
        float bv = (qrow >= 3) ? (kd ? bd : e1) : (kd ? e2 : e3);
        bv = (qrow == kcol) ? 0.f : bv;
        const float p = exp2f(fmaf(sc[f][r], 0.18033688011112042f, bv));
        rsum[r] += p;
        Ps[w][half][(l4 * 4 + r) * 136 + f * 16 + l15] = f2bf(p);
      }
    }

    // ---- PV: V frag loads in 2 batches of 8; P from wave-local LDS ----
#pragma unroll
    for (int qtr = 0; qtr < 2; ++qtr) {
      bf16x8_t vr[8];
#pragma unroll
      for (int i = 0; i < 8; ++i)
        vr[i] = *(const bf16x8_t*)(Vb_ + (size_t)(half * 16 + qtr * 8 + i) * 512);
#pragma unroll
      for (int kbl = 0; kbl < 2; ++kbl) {
        const bf16x8_t pf =
            *(const bf16x8_t*)&Ps[w][half][l15 * 136 + (qtr * 2 + kbl) * 32 + l4 * 8];
#pragma unroll
        for (int n = 0; n < 4; ++n) oacc[n] = MFMA16(pf, vr[kbl * 4 + n], oacc[n]);
      }
    }
  }

  // ---- row-sum reduce over l15 group, scale, store ----
#pragma unroll
  for (int m = 1; m < 16; m <<= 1)
#pragma unroll
    for (int r = 0; r < 4; ++r) rsum[r] += __shfl_xor(rsum[r], m, 64);
  float rinv[4];
#pragma unroll
  for (int r = 0; r < 4; ++r) rinv[r] = 1.0f / rsum[r];
  unsigned short* Op = O + (size_t)(b * 256 + qr0) * 1024 + h * 64;
#pragma unroll
  for (int n = 0; n < 4; ++n)
#pragma unroll
    for (int r = 0; r < 4; ++r)
      Op[(size_t)r * 1024 + n * 16 + l15] = f2bf(oacc[n][r] * rinv[r]);
}

extern "C" void kernel_launch(void* const* d_in, const int* in_sizes, int n_in,
                              void* d_out, int out_size, void* d_ws, size_t ws_size,
                              hipStream_t stream) {
  const float* x = (const float*)d_in[0];
  const int* state = (const int*)d_in[1];
  const float* WQ = (const float*)d_in[3];
  const float* WK = (const float*)d_in[4];
  const float* WV = (const float*)d_in[5];
  const float* WO = (const float*)d_in[6];
  const float* bO = (const float*)d_in[7];
  const float* etb = (const float*)d_in[8];
  const float* srb = (const float*)d_in[9];
  const float* rsb = (const float*)d_in[10];

  char* ws = (char*)d_ws;
  unsigned short* xn = (unsigned short*)(ws);                        // 32 MiB (reused as attn_out)
  unsigned short* Vf = (unsigned short*)(ws + (size_t)(32 << 20));   // 32 MiB (V fragments)
  unsigned short* WQKVb = (unsigned short*)(ws + (size_t)(64 << 20));// 6 MiB (WQ|WK|WV)
  unsigned short* WOb = WQKVb + (3 << 20);                           // 2 MiB
  // Q/K fragments: prefer d_ws (avoids d_out-as-scratch); deterministic
  // fallback to d_out regions if the workspace is too small.
  unsigned short* Qb;
  unsigned short* Kf;
  if (ws_size >= ((size_t)136 << 20)) {
    Qb = (unsigned short*)(ws + (size_t)(72 << 20));   // 32 MiB
    Kf = (unsigned short*)(ws + (size_t)(104 << 20));  // 32 MiB
  } else {
    Qb = (unsigned short*)d_out;
    Kf = Qb + (16 << 20);
  }

  cvt4_kernel<<<dim3(1024, 4), 256, 0, stream>>>(WQ, WK, WV, WO, WQKVb);
  ln_kernel<<<16384, 256, 0, stream>>>(x, xn);

  gemm_pipe<3><<<dim3(24, 64), 512, 0, stream>>>(xn, WQKVb, Qb, Kf, Vf, nullptr,
                                                 nullptr, nullptr, 24);

  attn_kernel<<<dim3(64, 64), 256, 0, stream>>>(Qb, Kf, Vf, xn, state, etb, srb, rsb);

  gemm_pipe<2><<<dim3(8, 64), 512, 0, stream>>>(xn, WOb, nullptr, nullptr, nullptr,
                                                (float*)d_out, bO, x, 8);
}

// Round 9
// 269.335 us; speedup vs baseline: 1.1965x; 1.0048x over previous
//
#include <hip/hip_runtime.h>
#include <hip/hip_bf16.h>
#include <stdint.h>

typedef float f32x4_t __attribute__((ext_vector_type(4)));
typedef short bf16x8_t __attribute__((ext_vector_type(8)));

#define MFMA16(a, b, c) __builtin_amdgcn_mfma_f32_16x16x32_bf16((a), (b), (c), 0, 0, 0)

static __device__ __forceinline__ unsigned short f2bf(float f) {
  union { float f; unsigned int u; } v;
  v.f = f;
  unsigned int u = v.u;
  unsigned int r = (u + 0x7fffu + ((u >> 16) & 1u)) >> 16;  // RNE
  return (unsigned short)r;
}

static __device__ __forceinline__ void gll16(const unsigned short* g, unsigned short* l) {
  __builtin_amdgcn_global_load_lds(
      (const __attribute__((address_space(1))) unsigned int*)g,
      (__attribute__((address_space(3))) unsigned int*)l, 16, 0, 0);
}

// ---------------- weights f32 -> bf16 (4 weights in one launch) ----------------
__global__ __launch_bounds__(256) void cvt4_kernel(const float* __restrict__ s0,
                                                   const float* __restrict__ s1,
                                                   const float* __restrict__ s2,
                                                   const float* __restrict__ s3,
                                                   unsigned short* __restrict__ dst) {
  const int i = blockIdx.x * 256 + threadIdx.x;  // < 262144
  const float* src = (blockIdx.y == 0) ? s0 : (blockIdx.y == 1) ? s1 : (blockIdx.y == 2) ? s2 : s3;
  float4 v = ((const float4*)src)[i];
  ushort4 o;
  o.x = f2bf(v.x); o.y = f2bf(v.y); o.z = f2bf(v.z); o.w = f2bf(v.w);
  ((ushort4*)(dst + (size_t)blockIdx.y * 1048576))[i] = o;
}

// ---------------- LayerNorm: x[row][1024] f32 -> xn bf16 ----------------
__global__ __launch_bounds__(256) void ln_kernel(const float* __restrict__ x,
                                                 unsigned short* __restrict__ xn) {
  const int row = blockIdx.x;
  const int tid = threadIdx.x, w = tid >> 6, lane = tid & 63;
  const float4 v = ((const float4*)(x + (size_t)row * 1024))[tid];
  float s = v.x + v.y + v.z + v.w;
  float s2 = v.x * v.x + v.y * v.y + v.z * v.z + v.w * v.w;
#pragma unroll
  for (int m = 32; m; m >>= 1) {
    s += __shfl_xor(s, m, 64);
    s2 += __shfl_xor(s2, m, 64);
  }
  __shared__ float red[2][4];
  if (lane == 0) { red[0][w] = s; red[1][w] = s2; }
  __syncthreads();
  const float S = red[0][0] + red[0][1] + red[0][2] + red[0][3];
  const float S2 = red[1][0] + red[1][1] + red[1][2] + red[1][3];
  const float mu = S * (1.0f / 1024.0f);
  const float var = S2 * (1.0f / 1024.0f) - mu * mu;
  const float rstd = rsqrtf(var + 1e-5f);
  ushort4 o;
  o.x = f2bf((v.x - mu) * rstd);
  o.y = f2bf((v.y - mu) * rstd);
  o.z = f2bf((v.z - mu) * rstd);
  o.w = f2bf((v.w - mu) * rstd);
  ((ushort4*)(xn + (size_t)row * 1024))[tid] = o;
}

// ---------------- pipelined GEMM: C[M][N] = A[M][K] * B[N][K]^T ----------------
// Tile 256(M) x 128(N) x BK=64. 512 thr = 8 waves (4M x 2N), wave owns 64x64.
// Ring of 3 LDS K-tile buffers; per iter: issue stage(t+2); consume(t);
// s_waitcnt vmcnt(6); s_barrier (R5 form — no sched_barrier pins).
// Never vmcnt(0) in main loop (T3+T4). Read-side chunk-XOR paired with
// pre-swizzled global staging source (T2/m173).
// MODE 3 epilogue: LDS-bounce per wave (9.2KB scratch, stride-72 rows) then
//   8 coalesced 1KB dwordx4 stores in fragment order (identical layouts to R8):
//   bn<8 -> Qb plain rows; bn<16 -> Kf frag; else Vf frag (transposed bounce).
// MODE 2: f32 d_out = acc + bias[col] + resid
template <int MODE>
__global__ __launch_bounds__(512, 1) void gemm_pipe(
    const unsigned short* __restrict__ A, const unsigned short* __restrict__ B,
    unsigned short* __restrict__ Qo, unsigned short* __restrict__ Ko,
    unsigned short* __restrict__ Vo, float* __restrict__ Cf,
    const float* __restrict__ bias, const float* __restrict__ resid, int GX) {
  constexpr int K = 1024;
  constexpr int NT = 16;  // K / 64
  __shared__ __align__(16) unsigned short lds[73728];  // A: 3*16384, B base 49152: 3*8192
  const int tid = threadIdx.x;
  const int wv = tid >> 6, lane = tid & 63;
  const int l15 = lane & 15, l4 = lane >> 4;
  const int wr = wv >> 1, wc = wv & 1;
  // bijective XCD swizzle (nwg % 8 == 0 for both grids)
  const int fid = blockIdx.y * GX + blockIdx.x;
  const int cpx = (GX * gridDim.y) >> 3;
  const int swz = (fid & 7) * cpx + (fid >> 3);
  const int bm = swz / GX, bn = swz % GX;

  // staging source: 8-lane groups cover one row's 8 chunks, chunk pre-XOR'd by row&7
  const int srow = wv * 8 + (lane >> 3);
  const int schunk = ((lane & 7) ^ (lane >> 3)) * 8;
  const unsigned short* Ag = A + (size_t)(bm * 256 + srow) * K + schunk;
  const unsigned short* Bg = B + (size_t)(bn * 128 + srow) * K + schunk;

  f32x4_t acc[4][4];
#pragma unroll
  for (int i = 0; i < 4; ++i)
#pragma unroll
    for (int j = 0; j < 4; ++j) acc[i][j] = (f32x4_t){0.f, 0.f, 0.f, 0.f};

#define STAGE(tt, slot)                                                          \
  {                                                                              \
    const unsigned short* As_ = Ag + (tt)*64;                                    \
    const unsigned short* Bs_ = Bg + (tt)*64;                                    \
    _Pragma("unroll") for (int r = 0; r < 4; ++r)                                \
        gll16(As_ + (size_t)(r * 64) * K, &lds[(slot)*16384 + r * 4096 + wv * 512]); \
    _Pragma("unroll") for (int r = 0; r < 2; ++r)                                \
        gll16(Bs_ + (size_t)(r * 64) * K,                                        \
              &lds[49152 + (slot)*8192 + r * 4096 + wv * 512]);                  \
  }

#define CONSUME(slot)                                                            \
  {                                                                              \
    const unsigned short* As_ = &lds[(slot)*16384];                              \
    const unsigned short* Bs_ = &lds[49152 + (slot)*8192];                       \
    _Pragma("unroll") for (int kk = 0; kk < 2; ++kk) {                           \
      const int cx = 8 * (((kk * 4 + l4) ^ (l15 & 7)));                          \
      bf16x8_t af[4], bf[4];                                                     \
      _Pragma("unroll") for (int m = 0; m < 4; ++m)                              \
          af[m] = *(const bf16x8_t*)&As_[(wr * 64 + m * 16 + l15) * 64 + cx];    \
      _Pragma("unroll") for (int n = 0; n < 4; ++n)                              \
          bf[n] = *(const bf16x8_t*)&Bs_[(wc * 64 + n * 16 + l15) * 64 + cx];    \
      __builtin_amdgcn_s_setprio(1);                                             \
      _Pragma("unroll") for (int m = 0; m < 4; ++m)                              \
          _Pragma("unroll") for (int n = 0; n < 4; ++n)                          \
              acc[m][n] = MFMA16(af[m], bf[n], acc[m][n]);                       \
      __builtin_amdgcn_s_setprio(0);                                             \
    }                                                                            \
  }

#define RING_SYNC(N)                                            \
  asm volatile("s_waitcnt vmcnt(" #N ")" ::: "memory");         \
  __builtin_amdgcn_s_barrier();                                 \
  asm volatile("" ::: "memory");

  STAGE(0, 0);
  STAGE(1, 1);
  RING_SYNC(6);

#pragma unroll 1
  for (int t = 0; t < NT - 2; ++t) {
    const int s = t % 3;
    const int sp = (t + 2) % 3;
    STAGE(t + 2, sp);
    CONSUME(s);
    RING_SYNC(6);
  }
  CONSUME((NT - 2) % 3);
  RING_SYNC(0);
  CONSUME((NT - 1) % 3);

#undef STAGE
#undef CONSUME
#undef RING_SYNC

  const int rbase = bm * 256 + wr * 64;
  const int cbase = bn * 128 + wc * 64;
  if constexpr (MODE == 3) {
    // ring reads done -> reuse LDS as per-wave bounce scratch (stride 72 shorts)
    asm volatile("s_waitcnt lgkmcnt(0)" ::: "memory");
    __builtin_amdgcn_s_barrier();
    unsigned short* sw = &lds[wv * 4608];  // 64 rows x 72 shorts = 9216 B/wave
    if (bn < 16) {
      // row-major scratch: sw[s_local*72 + d_local]
#pragma unroll
      for (int i = 0; i < 4; ++i)
#pragma unroll
        for (int j = 0; j < 4; ++j)
#pragma unroll
          for (int r = 0; r < 4; ++r)
            sw[(i * 16 + l4 * 4 + r) * 72 + j * 16 + l15] = f2bf(acc[i][j][r]);
      if (bn < 8) {  // Q: plain rows, 8 x (8 rows x 128B) coalesced stores
        const int qs = lane >> 3, qd = (lane & 7) * 8;
#pragma unroll
        for (int sg = 0; sg < 8; ++sg) {
          const bf16x8_t v = *(const bf16x8_t*)&sw[(sg * 8 + qs) * 72 + qd];
          *(bf16x8_t*)&Qo[(size_t)(rbase + sg * 8 + qs) * 1024 + cbase + qd] = v;
        }
      } else {  // K fragment groups: [(fgG*2+hd)*512 + lane*8]
        const int h = (bn - 8) * 2 + wc;
        unsigned short* Kfb = Ko + ((size_t)(bm * 16 + h)) * 16384;
#pragma unroll
        for (int fg = 0; fg < 4; ++fg)
#pragma unroll
          for (int hd = 0; hd < 2; ++hd) {
            const bf16x8_t v = *(const bf16x8_t*)&sw[(fg * 16 + l15) * 72 + hd * 32 + l4 * 8];
            *(bf16x8_t*)&Kfb[(size_t)((wr * 4 + fg) * 2 + hd) * 512 + lane * 8] = v;
          }
      }
    } else {  // V: transposed scratch sw[d_local*72 + s_local]
#pragma unroll
      for (int i = 0; i < 4; ++i)
#pragma unroll
        for (int j = 0; j < 4; ++j) {
          ushort4 pk;
          pk.x = f2bf(acc[i][j][0]); pk.y = f2bf(acc[i][j][1]);
          pk.z = f2bf(acc[i][j][2]); pk.w = f2bf(acc[i][j][3]);
          *(ushort4*)&sw[(j * 16 + l15) * 72 + i * 16 + l4 * 4] = pk;
        }
      const int h = (bn - 16) * 2 + wc;
      unsigned short* Vfb = Vo + ((size_t)(bm * 16 + h)) * 16384;
#pragma unroll
      for (int kb = 0; kb < 2; ++kb)
#pragma unroll
        for (int n = 0; n < 4; ++n) {
          const bf16x8_t v = *(const bf16x8_t*)&sw[(n * 16 + l15) * 72 + kb * 32 + l4 * 8];
          *(bf16x8_t*)&Vfb[(size_t)((wr * 2 + kb) * 4 + n) * 512 + lane * 8] = v;
        }
    }
  } else {  // MODE 2
#pragma unroll
    for (int i = 0; i < 4; ++i) {
      const int row0 = rbase + i * 16 + l4 * 4;
#pragma unroll
      for (int j = 0; j < 4; ++j) {
        const int col = cbase + j * 16 + l15;
        const float bo = bias[col];
#pragma unroll
        for (int r = 0; r < 4; ++r) {
          const size_t idx = (size_t)(row0 + r) * 1024 + col;
          Cf[idx] = acc[i][j][r] + bo + resid[idx];
        }
      }
    }
  }
}

// ---------------- fused attention: barrier-free wave tasks, coalesced frags ----
// grid (64, 64 b) x 256 thr. Wave task id = blockIdx.x*4 + w: h = id & 15,
// q-chunk = id >> 4 (16 rows). K/V in fragment order -> every load is
// base + lane*16B (1KB coalesced per instruction), batched 8 at a time.
// Ps double-buffered per half (no WAR reuse). No main-loop barriers.
__global__ __launch_bounds__(256, 4) void attn_kernel(
    const unsigned short* __restrict__ Q, const unsigned short* __restrict__ Kf,
    const unsigned short* __restrict__ Vf, unsigned short* __restrict__ O,
    const int* __restrict__ state, const float* __restrict__ etb,
    const float* __restrict__ srb, const float* __restrict__ rsb) {
  const int b = blockIdx.y;
  const int tid = threadIdx.x, w = tid >> 6, lane = tid & 63;
  const int l15 = lane & 15, l4 = lane >> 4;
  const int id = blockIdx.x * 4 + w;  // 0..255
  const int h = id & 15;
  const int qrow0 = (id >> 4) * 16;

  __shared__ __align__(16) unsigned short Ps[4][2][16 * 136];  // 34.8 KB, dbuf per half
  __shared__ int state_s[256];                                 // 1 KB

  state_s[tid] = (tid >= 3) ? state[b * 253 + tid - 3] : 0x7fffffff;
  constexpr float L2E = 1.4426950408889634f;
  const float e0 = etb[0] * L2E, e1 = etb[1] * L2E, e2 = etb[2] * L2E, e3 = etb[3] * L2E;
  const float sr0 = srb[0] * L2E, sr1 = srb[1] * L2E;
  const float rs0 = rsb[0] * L2E, rs2 = rsb[2] * L2E;
  __syncthreads();

  const size_t qoff = (size_t)(b * 256 + qrow0 + l15) * 1024 + h * 64 + l4 * 8;
  const bf16x8_t qf0 = *(const bf16x8_t*)(Q + qoff);
  const bf16x8_t qf1 = *(const bf16x8_t*)(Q + qoff + 32);

  const unsigned short* Kb_ = Kf + ((size_t)(b * 16 + h)) * 16384 + lane * 8;
  const unsigned short* Vb_ = Vf + ((size_t)(b * 16 + h)) * 16384 + lane * 8;

  const int qr0 = qrow0 + l4 * 4;
  int sq[4];
#pragma unroll
  for (int r = 0; r < 4; ++r) sq[r] = state_s[qr0 + r];

  f32x4_t oacc[4];
#pragma unroll
  for (int n = 0; n < 4; ++n) oacc[n] = (f32x4_t){0.f, 0.f, 0.f, 0.f};
  float rsum[4] = {0.f, 0.f, 0.f, 0.f};

#pragma unroll
  for (int half = 0; half < 2; ++half) {
    // ---- QK^T for 128 k-cols: K frag loads in 2 batches of 8 (8KB seq each) ----
    f32x4_t sc[8];
#pragma unroll
    for (int f = 0; f < 8; ++f) sc[f] = (f32x4_t){0.f, 0.f, 0.f, 0.f};
#pragma unroll
    for (int qtr = 0; qtr < 2; ++qtr) {
      bf16x8_t kr[8];
#pragma unroll
      for (int i = 0; i < 8; ++i)
        kr[i] = *(const bf16x8_t*)(Kb_ + (size_t)(half * 16 + qtr * 8 + i) * 512);
#pragma unroll
      for (int f = 0; f < 4; ++f) {
        sc[qtr * 4 + f] = MFMA16(qf0, kr[2 * f], sc[qtr * 4 + f]);
        sc[qtr * 4 + f] = MFMA16(qf1, kr[2 * f + 1], sc[qtr * 4 + f]);
      }
    }

    // ---- bias + exp2 + unnormalized P write + partial row-sum ----
#pragma unroll
    for (int f = 0; f < 8; ++f) {
      const int kcol = half * 128 + f * 16 + l15;
      const bool kd = kcol >= 3;
      const int skc = state_s[kcol];
#pragma unroll
      for (int r = 0; r < 4; ++r) {
        const int qrow = qr0 + r;
        float bd = e0 + ((skc == sq[r]) ? sr0 : sr1) + ((qrow < kcol) ? rs0 : rs2);
        float bv = (qrow >= 3) ? (kd ? bd : e1) : (kd ? e2 : e3);
        bv = (qrow == kcol) ? 0.f : bv;
        const float p = exp2f(fmaf(sc[f][r], 0.18033688011112042f, bv));
        rsum[r] += p;
        Ps[w][half][(l4 * 4 + r) * 136 + f * 16 + l15] = f2bf(p);
      }
    }

    // ---- PV: V frag loads in 2 batches of 8; P from wave-local LDS ----
#pragma unroll
    for (int qtr = 0; qtr < 2; ++qtr) {
      bf16x8_t vr[8];
#pragma unroll
      for (int i = 0; i < 8; ++i)
        vr[i] = *(const bf16x8_t*)(Vb_ + (size_t)(half * 16 + qtr * 8 + i) * 512);
#pragma unroll
      for (int kbl = 0; kbl < 2; ++kbl) {
        const bf16x8_t pf =
            *(const bf16x8_t*)&Ps[w][half][l15 * 136 + (qtr * 2 + kbl) * 32 + l4 * 8];
#pragma unroll
        for (int n = 0; n < 4; ++n) oacc[n] = MFMA16(pf, vr[kbl * 4 + n], oacc[n]);
      }
    }
  }

  // ---- row-sum reduce over l15 group, scale, store ----
#pragma unroll
  for (int m = 1; m < 16; m <<= 1)
#pragma unroll
    for (int r = 0; r < 4; ++r) rsum[r] += __shfl_xor(rsum[r], m, 64);
  float rinv[4];
#pragma unroll
  for (int r = 0; r < 4; ++r) rinv[r] = 1.0f / rsum[r];
  unsigned short* Op = O + (size_t)(b * 256 + qr0) * 1024 + h * 64;
#pragma unroll
  for (int n = 0; n < 4; ++n)
#pragma unroll
    for (int r = 0; r < 4; ++r)
      Op[(size_t)r * 1024 + n * 16 + l15] = f2bf(oacc[n][r] * rinv[r]);
}

extern "C" void kernel_launch(void* const* d_in, const int* in_sizes, int n_in,
                              void* d_out, int out_size, void* d_ws, size_t ws_size,
                              hipStream_t stream) {
  const float* x = (const float*)d_in[0];
  const int* state = (const int*)d_in[1];
  const float* WQ = (const float*)d_in[3];
  const float* WK = (const float*)d_in[4];
  const float* WV = (const float*)d_in[5];
  const float* WO = (const float*)d_in[6];
  const float* bO = (const float*)d_in[7];
  const float* etb = (const float*)d_in[8];
  const float* srb = (const float*)d_in[9];
  const float* rsb = (const float*)d_in[10];

  char* ws = (char*)d_ws;
  unsigned short* xn = (unsigned short*)(ws);                        // 32 MiB (reused as attn_out)
  unsigned short* Vf = (unsigned short*)(ws + (size_t)(32 << 20));   // 32 MiB (V fragments)
  unsigned short* WQKVb = (unsigned short*)(ws + (size_t)(64 << 20));// 6 MiB (WQ|WK|WV)
  unsigned short* WOb = WQKVb + (3 << 20);                           // 2 MiB
  // Q/K fragments: prefer d_ws (avoids d_out-as-scratch); deterministic
  // fallback to d_out regions if the workspace is too small.
  unsigned short* Qb;
  unsigned short* Kf;
  if (ws_size >= ((size_t)136 << 20)) {
    Qb = (unsigned short*)(ws + (size_t)(72 << 20));   // 32 MiB
    Kf = (unsigned short*)(ws + (size_t)(104 << 20));  // 32 MiB
  } else {
    Qb = (unsigned short*)d_out;
    Kf = Qb + (16 << 20);
  }

  cvt4_kernel<<<dim3(1024, 4), 256, 0, stream>>>(WQ, WK, WV, WO, WQKVb);
  ln_kernel<<<16384, 256, 0, stream>>>(x, xn);

  gemm_pipe<3><<<dim3(24, 64), 512, 0, stream>>>(xn, WQKVb, Qb, Kf, Vf, nullptr,
                                                 nullptr, nullptr, 24);

  attn_kernel<<<dim3(64, 64), 256, 0, stream>>>(Qb, Kf, Vf, xn, state, etb, srb, rsb);

  gemm_pipe<2><<<dim3(8, 64), 512, 0, stream>>>(xn, WOb, nullptr, nullptr, nullptr,
                                                (float*)d_out, bO, x, 8);
}